// Round 1
// baseline (2926.248 us; speedup 1.0000x reference)
//
#include <hip/hip_runtime.h>

// Fuzzy c-means on MI355X. N=300000, D=64, c=64, m=2 (p=2), 25 updates + init.
// Structure: U is never materialized. Each update pass fuses membership
// computation and center accumulation in one kernel; lane = cluster j.
// Deterministic reductions (butterfly + fixed-order partial sums), fp32 only.

#define DM 64
#define CL 64
#define UPD_BLOCKS 586           // 586 blocks x 4 waves = 2344 waves; 4688 tiles -> 2 tiles/wave exact
#define PARTIAL_STRIDE 4160      // 64*64 num + 64 den
#define MAX_ITER 25

__device__ __forceinline__ float wave_sum(float v) {
#pragma unroll
  for (int off = 32; off; off >>= 1) v += __shfl_xor(v, off, 64);
  return v;
}

// rcp + one Newton step: ~fp32-accurate reciprocal, 3 instrs instead of IEEE div sequence
__device__ __forceinline__ float fast_rcp(float x) {
  float r = __builtin_amdgcn_rcpf(x);
  return r * (2.0f - x * r);
}

// x2[i] = ||x_i||^2 precompute + flag/diff reset (runs first on the stream)
__global__ void fcm_prep(const float* __restrict__ data, float* __restrict__ x2,
                         float* __restrict__ diffac, int* __restrict__ done, int N) {
  int i = blockIdx.x * blockDim.x + threadIdx.x;
  if (i == 0) { *diffac = 0.0f; *done = 0; }
  if (i < N) {
    const float4* r = (const float4*)(data + (size_t)i * DM);
    float s = 0.0f;
#pragma unroll
    for (int q = 0; q < DM / 4; q++) {
      float4 v = r[q];
      s = fmaf(v.x, v.x, s); s = fmaf(v.y, v.y, s);
      s = fmaf(v.z, v.z, s); s = fmaf(v.w, v.w, s);
    }
    x2[i] = s;
  }
}

// Block-level reduction of per-wave accumulators -> per-block partial in global ws.
// LDS rows padded to 66 floats: banks (2*lane+d)%32 -> worst 2-way (free on CDNA4).
__device__ __forceinline__ void block_reduce_store(float* red, const float* acc, float den,
                                                   float* __restrict__ partial) {
  int lane = threadIdx.x & 63;
  int w = threadIdx.x >> 6;
  int nw = blockDim.x >> 6;
  for (int ww = 0; ww < nw; ww++) {
    if (w == ww) {
      if (ww == 0) {
#pragma unroll
        for (int d = 0; d < DM; d++) red[lane * 66 + d] = acc[d];
        red[64 * 66 + lane] = den;
      } else {
#pragma unroll
        for (int d = 0; d < DM; d++) red[lane * 66 + d] += acc[d];
        red[64 * 66 + lane] += den;
      }
    }
    __syncthreads();
  }
  float* pb = partial + (size_t)blockIdx.x * PARTIAL_STRIDE;
  for (int i = threadIdx.x; i < CL * DM; i += blockDim.x)
    pb[i] = red[(i >> 6) * 66 + (i & 63)];
  if (threadIdx.x < 64) pb[CL * DM + threadIdx.x] = red[64 * 66 + threadIdx.x];
}

// C_0 partials: membership from normalized u0_raw, squared, accumulate um * x.
__global__ __launch_bounds__(256, 2)
void fcm_init(const float* __restrict__ data, const float* __restrict__ u0,
              float* __restrict__ partial, int N, int ntiles, int totwaves) {
  __shared__ float red[64 * 66 + 64];
  int lane = threadIdx.x & 63;
  int wv = blockIdx.x * (blockDim.x >> 6) + __builtin_amdgcn_readfirstlane(threadIdx.x >> 6);
  float acc[DM];
#pragma unroll
  for (int d = 0; d < DM; d++) acc[d] = 0.0f;
  float den = 0.0f;
  for (int t = wv; t < ntiles; t += totwaves) {
    int base = t * 64;
    int np = min(64, N - base);
    for (int p = 0; p < np; p++) {
      int pt = base + p;                       // wave-uniform
      float u = u0[(size_t)pt * CL + lane];    // coalesced
      float s = wave_sum(u);
      float un = u * fast_rcp(s);
      float um = un * un;
      den += um;
      const float* xr = data + (size_t)pt * DM;  // wave-uniform row -> scalar loads
#pragma unroll
      for (int d = 0; d < DM; d++) acc[d] = fmaf(um, xr[d], acc[d]);
    }
  }
  block_reduce_store(red, acc, den, partial);
}

// One fused FCM update pass: C_cur -> partials for C_next. Lane j owns cluster j.
__global__ __launch_bounds__(256, 2)
void fcm_update(const float* __restrict__ data, const float* __restrict__ x2,
                const float* __restrict__ Ccur, float* __restrict__ partial,
                const int* __restrict__ done, int N, int ntiles, int totwaves) {
  if (*done) return;   // frozen after convergence (wave-uniform)
  __shared__ float red[64 * 66 + 64];
  int lane = threadIdx.x & 63;
  int wv = blockIdx.x * (blockDim.x >> 6) + __builtin_amdgcn_readfirstlane(threadIdx.x >> 6);
  float Crow[DM];
#pragma unroll
  for (int d = 0; d < DM; d++) Crow[d] = Ccur[lane * DM + d];
  float c2 = 0.0f;
#pragma unroll
  for (int d = 0; d < DM; d++) c2 = fmaf(Crow[d], Crow[d], c2);
  float acc[DM];
#pragma unroll
  for (int d = 0; d < DM; d++) acc[d] = 0.0f;
  float den = 0.0f;
  for (int t = wv; t < ntiles; t += totwaves) {
    int base = t * 64;
    int np = min(64, N - base);
    for (int p = 0; p < np; p++) {
      int pt = base + p;                          // wave-uniform
      const float* xr = data + (size_t)pt * DM;   // wave-uniform row
      // dot(x_p, C_j): 4 independent FMA chains for ILP
      float d0 = 0.0f, d1 = 0.0f, d2 = 0.0f, d3 = 0.0f;
#pragma unroll
      for (int q = 0; q < DM / 4; q++) {
        d0 = fmaf(Crow[4 * q + 0], xr[4 * q + 0], d0);
        d1 = fmaf(Crow[4 * q + 1], xr[4 * q + 1], d1);
        d2 = fmaf(Crow[4 * q + 2], xr[4 * q + 2], d2);
        d3 = fmaf(Crow[4 * q + 3], xr[4 * q + 3], d3);
      }
      float dot = (d0 + d1) + (d2 + d3);
      float dist = fmaxf(x2[pt] + c2 - 2.0f * dot, 0.0f);  // jnp.maximum(...,0)
      float wgt = fast_rcp(dist);                // d^(-p/2) with p=2
      float s = wave_sum(wgt);                   // row sum across the 64 clusters
      float u = wgt * fast_rcp(s);
      float um = u * u;                          // U^m, m=2
      den += um;
#pragma unroll
      for (int d = 0; d < DM; d++) acc[d] = fmaf(um, xr[d], acc[d]);
    }
  }
  block_reduce_store(red, acc, den, partial);
}

// Sum partials -> C_new; optionally accumulate squared Frobenius diff vs C_old.
__global__ void fcm_reduce(const float* __restrict__ partial, float* __restrict__ Cnew,
                           const float* __restrict__ Cold, float* __restrict__ diffac,
                           const int* __restrict__ done, int compute_diff, int nb) {
  if (compute_diff && *done) return;
  int j = blockIdx.x;
  int d = threadIdx.x;
  float s = 0.0f;
  for (int b = 0; b < nb; b++) s += partial[(size_t)b * PARTIAL_STRIDE + j * DM + d];
  float dp = 0.0f;
  for (int b = d; b < nb; b += 64) dp += partial[(size_t)b * PARTIAL_STRIDE + CL * DM + j];
  float denj = wave_sum(dp);
  float c = s / denj;
  Cnew[j * DM + d] = c;
  if (compute_diff) {
    float df = c - Cold[j * DM + d];
    float tot = wave_sum(df * df);
    if (d == 0) atomicAdd(diffac, tot);
  }
}

// Convergence check: on first diff < EPS, freeze and emit V = C_old (pre-update center).
__global__ void fcm_check(const float* __restrict__ Cold, float* __restrict__ out,
                          float* __restrict__ diffac, int* __restrict__ done) {
  __shared__ int sdone;
  __shared__ float sdiff;
  if (threadIdx.x == 0) { sdone = *done; sdiff = *diffac; }
  __syncthreads();
  if (!sdone && sdiff < 1e-16f) {    // diff < 1e-8  <=>  diff^2 < 1e-16
    for (int i = threadIdx.x; i < CL * DM; i += blockDim.x) out[i] = Cold[i];
    if (threadIdx.x == 0) *done = 1;
  }
  __syncthreads();
  if (threadIdx.x == 0) *diffac = 0.0f;
}

// If never converged, V = C_25.
__global__ void fcm_final(const float* __restrict__ Clast, float* __restrict__ out,
                          const int* __restrict__ done) {
  if (*done) return;
  int i = blockIdx.x * blockDim.x + threadIdx.x;
  if (i < CL * DM) out[i] = Clast[i];
}

extern "C" void kernel_launch(void* const* d_in, const int* in_sizes, int n_in,
                              void* d_out, int out_size, void* d_ws, size_t ws_size,
                              hipStream_t stream) {
  const float* data = (const float*)d_in[0];
  const float* u0   = (const float*)d_in[1];
  float* out = (float*)d_out;
  int N = in_sizes[0] / DM;            // 300000
  int ntiles = (N + 63) / 64;          // 4688
  int totwaves = UPD_BLOCKS * 4;       // 2344 -> exactly 2 tiles per wave

  // workspace carve (floats); total ~11 MB
  float* ws = (float*)d_ws;
  float* x2 = ws;                                  // N
  float* C0 = ws + ((N + 15) & ~15);               // 4096
  float* C1 = C0 + CL * DM;                        // 4096
  float* diffac = C1 + CL * DM;                    // 1
  int* done = (int*)(diffac + 1);                  // 1
  float* partial = diffac + 8;                     // UPD_BLOCKS * 4160

  hipLaunchKernelGGL(fcm_prep, dim3((N + 255) / 256), dim3(256), 0, stream,
                     data, x2, diffac, done, N);
  hipLaunchKernelGGL(fcm_init, dim3(UPD_BLOCKS), dim3(256), 0, stream,
                     data, u0, partial, N, ntiles, totwaves);
  hipLaunchKernelGGL(fcm_reduce, dim3(64), dim3(64), 0, stream,
                     partial, C0, C1, diffac, done, 0, UPD_BLOCKS);

  float* bufs[2] = {C0, C1};
  for (int k = 0; k < MAX_ITER; k++) {
    float* Cc = bufs[k & 1];
    float* Cn = bufs[(k + 1) & 1];
    hipLaunchKernelGGL(fcm_update, dim3(UPD_BLOCKS), dim3(256), 0, stream,
                       data, x2, Cc, partial, done, N, ntiles, totwaves);
    hipLaunchKernelGGL(fcm_reduce, dim3(64), dim3(64), 0, stream,
                       partial, Cn, Cc, diffac, done, 1, UPD_BLOCKS);
    hipLaunchKernelGGL(fcm_check, dim3(1), dim3(256), 0, stream,
                       Cc, out, diffac, done);
  }
  hipLaunchKernelGGL(fcm_final, dim3(16), dim3(256), 0, stream,
                     bufs[1], out, done);
}

// Round 2
// 1482.532 us; speedup vs baseline: 1.9738x; 1.9738x over previous
//
#include <hip/hip_runtime.h>

// Fuzzy c-means on MI355X. N=300000, D=64, c=64, m=2 (p=2), 25 updates + init.
// U never materialized; update pass fuses membership + center accumulation.
// R1 change: fcm_reduce was the bottleneck (145us x26, 0.7% occupancy, 586-long
// serial load chain per thread). Now 64 blocks x 1024 threads, 16-way sliced
// partial sums + deterministic LDS tree. Everything else unchanged.

#define DM 64
#define CL 64
#define UPD_BLOCKS 586           // 586 blocks x 4 waves = 2344 waves; 4688 tiles -> 2 tiles/wave exact
#define PARTIAL_STRIDE 4160      // 64*64 num + 64 den
#define MAX_ITER 25

__device__ __forceinline__ float wave_sum(float v) {
#pragma unroll
  for (int off = 32; off; off >>= 1) v += __shfl_xor(v, off, 64);
  return v;
}

// rcp + one Newton step: ~fp32-accurate reciprocal
__device__ __forceinline__ float fast_rcp(float x) {
  float r = __builtin_amdgcn_rcpf(x);
  return r * (2.0f - x * r);
}

// x2[i] = ||x_i||^2 precompute + flag/diff reset (runs first on the stream)
__global__ void fcm_prep(const float* __restrict__ data, float* __restrict__ x2,
                         float* __restrict__ diffac, int* __restrict__ done, int N) {
  int i = blockIdx.x * blockDim.x + threadIdx.x;
  if (i == 0) { *diffac = 0.0f; *done = 0; }
  if (i < N) {
    const float4* r = (const float4*)(data + (size_t)i * DM);
    float s = 0.0f;
#pragma unroll
    for (int q = 0; q < DM / 4; q++) {
      float4 v = r[q];
      s = fmaf(v.x, v.x, s); s = fmaf(v.y, v.y, s);
      s = fmaf(v.z, v.z, s); s = fmaf(v.w, v.w, s);
    }
    x2[i] = s;
  }
}

// Block-level reduction of per-wave accumulators -> per-block partial in global ws.
__device__ __forceinline__ void block_reduce_store(float* red, const float* acc, float den,
                                                   float* __restrict__ partial) {
  int lane = threadIdx.x & 63;
  int w = threadIdx.x >> 6;
  int nw = blockDim.x >> 6;
  for (int ww = 0; ww < nw; ww++) {
    if (w == ww) {
      if (ww == 0) {
#pragma unroll
        for (int d = 0; d < DM; d++) red[lane * 66 + d] = acc[d];
        red[64 * 66 + lane] = den;
      } else {
#pragma unroll
        for (int d = 0; d < DM; d++) red[lane * 66 + d] += acc[d];
        red[64 * 66 + lane] += den;
      }
    }
    __syncthreads();
  }
  float* pb = partial + (size_t)blockIdx.x * PARTIAL_STRIDE;
  for (int i = threadIdx.x; i < CL * DM; i += blockDim.x)
    pb[i] = red[(i >> 6) * 66 + (i & 63)];
  if (threadIdx.x < 64) pb[CL * DM + threadIdx.x] = red[64 * 66 + threadIdx.x];
}

// C_0 partials: membership from normalized u0_raw, squared, accumulate um * x.
__global__ __launch_bounds__(256, 2)
void fcm_init(const float* __restrict__ data, const float* __restrict__ u0,
              float* __restrict__ partial, int N, int ntiles, int totwaves) {
  __shared__ float red[64 * 66 + 64];
  int lane = threadIdx.x & 63;
  int wv = blockIdx.x * (blockDim.x >> 6) + __builtin_amdgcn_readfirstlane(threadIdx.x >> 6);
  float acc[DM];
#pragma unroll
  for (int d = 0; d < DM; d++) acc[d] = 0.0f;
  float den = 0.0f;
  for (int t = wv; t < ntiles; t += totwaves) {
    int base = t * 64;
    int np = min(64, N - base);
    for (int p = 0; p < np; p++) {
      int pt = base + p;                       // wave-uniform
      float u = u0[(size_t)pt * CL + lane];    // coalesced
      float s = wave_sum(u);
      float un = u * fast_rcp(s);
      float um = un * un;
      den += um;
      const float* xr = data + (size_t)pt * DM;  // wave-uniform row -> scalar loads
#pragma unroll
      for (int d = 0; d < DM; d++) acc[d] = fmaf(um, xr[d], acc[d]);
    }
  }
  block_reduce_store(red, acc, den, partial);
}

// One fused FCM update pass: C_cur -> partials for C_next. Lane j owns cluster j.
__global__ __launch_bounds__(256, 2)
void fcm_update(const float* __restrict__ data, const float* __restrict__ x2,
                const float* __restrict__ Ccur, float* __restrict__ partial,
                const int* __restrict__ done, int N, int ntiles, int totwaves) {
  if (*done) return;   // frozen after convergence (wave-uniform)
  __shared__ float red[64 * 66 + 64];
  int lane = threadIdx.x & 63;
  int wv = blockIdx.x * (blockDim.x >> 6) + __builtin_amdgcn_readfirstlane(threadIdx.x >> 6);
  float Crow[DM];
#pragma unroll
  for (int d = 0; d < DM; d++) Crow[d] = Ccur[lane * DM + d];
  float c2 = 0.0f;
#pragma unroll
  for (int d = 0; d < DM; d++) c2 = fmaf(Crow[d], Crow[d], c2);
  float acc[DM];
#pragma unroll
  for (int d = 0; d < DM; d++) acc[d] = 0.0f;
  float den = 0.0f;
  for (int t = wv; t < ntiles; t += totwaves) {
    int base = t * 64;
    int np = min(64, N - base);
    for (int p = 0; p < np; p++) {
      int pt = base + p;                          // wave-uniform
      const float* xr = data + (size_t)pt * DM;   // wave-uniform row
      float d0 = 0.0f, d1 = 0.0f, d2 = 0.0f, d3 = 0.0f;
#pragma unroll
      for (int q = 0; q < DM / 4; q++) {
        d0 = fmaf(Crow[4 * q + 0], xr[4 * q + 0], d0);
        d1 = fmaf(Crow[4 * q + 1], xr[4 * q + 1], d1);
        d2 = fmaf(Crow[4 * q + 2], xr[4 * q + 2], d2);
        d3 = fmaf(Crow[4 * q + 3], xr[4 * q + 3], d3);
      }
      float dot = (d0 + d1) + (d2 + d3);
      float dist = fmaxf(x2[pt] + c2 - 2.0f * dot, 0.0f);  // jnp.maximum(...,0)
      float wgt = fast_rcp(dist);                // d^(-p/2) with p=2
      float s = wave_sum(wgt);                   // row sum across the 64 clusters
      float u = wgt * fast_rcp(s);
      float um = u * u;                          // U^m, m=2
      den += um;
#pragma unroll
      for (int d = 0; d < DM; d++) acc[d] = fmaf(um, xr[d], acc[d]);
    }
  }
  block_reduce_store(red, acc, den, partial);
}

// Sum partials -> C_new; optionally accumulate squared Frobenius diff vs C_old.
// R1: 64 blocks x 1024 threads. 16 slices of ~37 coalesced partial reads each,
// deterministic LDS trees, wave-0 finishes (divide + diff).
__global__ __launch_bounds__(1024, 1)
void fcm_reduce(const float* __restrict__ partial, float* __restrict__ Cnew,
                const float* __restrict__ Cold, float* __restrict__ diffac,
                const int* __restrict__ done, int compute_diff, int nb) {
  if (compute_diff && *done) return;
  __shared__ float sm[16 * 64];
  __shared__ float sden[1024];
  int j = blockIdx.x;
  int tid = threadIdx.x;
  int d = tid & 63;
  int slice = tid >> 6;                 // 0..15
  float s = 0.0f;
  for (int b = slice; b < nb; b += 16)  // coalesced: 64 consecutive floats per wave
    s += partial[(size_t)b * PARTIAL_STRIDE + j * DM + d];
  sm[slice * 64 + d] = s;
  float dv = 0.0f;
  for (int b = tid; b < nb; b += 1024)
    dv += partial[(size_t)b * PARTIAL_STRIDE + CL * DM + j];
  sden[tid] = dv;
  __syncthreads();
#pragma unroll
  for (int st = 8; st; st >>= 1) {
    if (slice < st) sm[slice * 64 + d] += sm[(slice + st) * 64 + d];
    __syncthreads();
  }
#pragma unroll
  for (int st = 512; st >= 64; st >>= 1) {
    if (tid < st) sden[tid] += sden[tid + st];
    __syncthreads();
  }
  if (tid < 64) {
    float denj = wave_sum(sden[tid]);   // all 64 lanes -> total den for cluster j
    float c = sm[tid] / denj;           // slice-0 row of sm holds the full sum
    Cnew[j * DM + tid] = c;
    if (compute_diff) {
      float df = c - Cold[j * DM + tid];
      float tot = wave_sum(df * df);
      if (tid == 0) atomicAdd(diffac, tot);
    }
  }
}

// Convergence check: on first diff < EPS, freeze and emit V = C_old (pre-update center).
__global__ void fcm_check(const float* __restrict__ Cold, float* __restrict__ out,
                          float* __restrict__ diffac, int* __restrict__ done) {
  __shared__ int sdone;
  __shared__ float sdiff;
  if (threadIdx.x == 0) { sdone = *done; sdiff = *diffac; }
  __syncthreads();
  if (!sdone && sdiff < 1e-16f) {    // diff < 1e-8  <=>  diff^2 < 1e-16
    for (int i = threadIdx.x; i < CL * DM; i += blockDim.x) out[i] = Cold[i];
    if (threadIdx.x == 0) *done = 1;
  }
  __syncthreads();
  if (threadIdx.x == 0) *diffac = 0.0f;
}

// If never converged, V = C_25.
__global__ void fcm_final(const float* __restrict__ Clast, float* __restrict__ out,
                          const int* __restrict__ done) {
  if (*done) return;
  int i = blockIdx.x * blockDim.x + threadIdx.x;
  if (i < CL * DM) out[i] = Clast[i];
}

extern "C" void kernel_launch(void* const* d_in, const int* in_sizes, int n_in,
                              void* d_out, int out_size, void* d_ws, size_t ws_size,
                              hipStream_t stream) {
  const float* data = (const float*)d_in[0];
  const float* u0   = (const float*)d_in[1];
  float* out = (float*)d_out;
  int N = in_sizes[0] / DM;            // 300000
  int ntiles = (N + 63) / 64;          // 4688
  int totwaves = UPD_BLOCKS * 4;       // 2344 -> exactly 2 tiles per wave

  float* ws = (float*)d_ws;
  float* x2 = ws;                                  // N
  float* C0 = ws + ((N + 15) & ~15);               // 4096
  float* C1 = C0 + CL * DM;                        // 4096
  float* diffac = C1 + CL * DM;                    // 1
  int* done = (int*)(diffac + 1);                  // 1
  float* partial = diffac + 8;                     // UPD_BLOCKS * 4160

  hipLaunchKernelGGL(fcm_prep, dim3((N + 255) / 256), dim3(256), 0, stream,
                     data, x2, diffac, done, N);
  hipLaunchKernelGGL(fcm_init, dim3(UPD_BLOCKS), dim3(256), 0, stream,
                     data, u0, partial, N, ntiles, totwaves);
  hipLaunchKernelGGL(fcm_reduce, dim3(64), dim3(1024), 0, stream,
                     partial, C0, C1, diffac, done, 0, UPD_BLOCKS);

  float* bufs[2] = {C0, C1};
  for (int k = 0; k < MAX_ITER; k++) {
    float* Cc = bufs[k & 1];
    float* Cn = bufs[(k + 1) & 1];
    hipLaunchKernelGGL(fcm_update, dim3(UPD_BLOCKS), dim3(256), 0, stream,
                       data, x2, Cc, partial, done, N, ntiles, totwaves);
    hipLaunchKernelGGL(fcm_reduce, dim3(64), dim3(1024), 0, stream,
                       partial, Cn, Cc, diffac, done, 1, UPD_BLOCKS);
    hipLaunchKernelGGL(fcm_check, dim3(1), dim3(256), 0, stream,
                       Cc, out, diffac, done);
  }
  hipLaunchKernelGGL(fcm_final, dim3(16), dim3(256), 0, stream,
                     bufs[1], out, done);
}

// Round 3
// 1353.312 us; speedup vs baseline: 2.1623x; 1.0955x over previous
//
#include <hip/hip_runtime.h>

// Fuzzy c-means on MI355X. N=300000, D=64, c=64, m=2 (p=2), 25 updates + init.
// R2 postmortem: fcm_update latency-bound (VALUBusy 34%): __shfl_xor = ds_bpermute
// serial chain (~200cyc/point) + scalar fp32 FMAs + under-filled residency.
// R3: DPP wave reduction (VALU pipe), packed float2 FMAs (v_pk_fma_f32),
// 768 blocks (runtime-clamped to ws_size), check merged into reduce (ticket).

#define DM 64
#define CL 64
#define PARTIAL_STRIDE 4160      // 64*64 num + 64 den
#define MAX_ITER 25
#define MAX_BLOCKS 768

typedef __attribute__((ext_vector_type(2))) float f32x2;

// Full-wave (64-lane) sum, all in the VALU pipe via DPP; result broadcast via readlane.
// Sequence: row_shr 1,2,4,8 (row-local inclusive sums), row_bcast:15 (rows 1,3),
// row_bcast:31 (rows 2,3) -> lane 63 holds the total.
__device__ __forceinline__ float wave_sum(float v) {
#define DPPADD(ctrl, rmask)                                                  \
  v += __builtin_bit_cast(float, __builtin_amdgcn_update_dpp(                \
           0, __builtin_bit_cast(int, v), ctrl, rmask, 0xf, false));
  DPPADD(0x111, 0xf)   // row_shr:1
  DPPADD(0x112, 0xf)   // row_shr:2
  DPPADD(0x114, 0xf)   // row_shr:4
  DPPADD(0x118, 0xf)   // row_shr:8
  DPPADD(0x142, 0xa)   // row_bcast:15 -> rows 1,3
  DPPADD(0x143, 0xc)   // row_bcast:31 -> rows 2,3
#undef DPPADD
  return __builtin_bit_cast(
      float, __builtin_amdgcn_readlane(__builtin_bit_cast(int, v), 63));
}

// rcp + one Newton step: ~fp32-accurate reciprocal
__device__ __forceinline__ float fast_rcp(float x) {
  float r = __builtin_amdgcn_rcpf(x);
  return r * (2.0f - x * r);
}

// x2[i] = ||x_i||^2 precompute + flag reset (runs first on the stream)
__global__ void fcm_prep(const float* __restrict__ data, float* __restrict__ x2,
                         float* __restrict__ diffac, int* __restrict__ done,
                         int* __restrict__ ticket, int N) {
  int i = blockIdx.x * blockDim.x + threadIdx.x;
  if (i == 0) { *diffac = 0.0f; *done = 0; *ticket = 0; }
  if (i < N) {
    const float4* r = (const float4*)(data + (size_t)i * DM);
    float s = 0.0f;
#pragma unroll
    for (int q = 0; q < DM / 4; q++) {
      float4 v = r[q];
      s = fmaf(v.x, v.x, s); s = fmaf(v.y, v.y, s);
      s = fmaf(v.z, v.z, s); s = fmaf(v.w, v.w, s);
    }
    x2[i] = s;
  }
}

// Block-level reduction of per-wave accumulators -> per-block partial in global ws.
__device__ __forceinline__ void block_reduce_store(float* red, const f32x2* acc2,
                                                   float den, float* __restrict__ partial) {
  int lane = threadIdx.x & 63;
  int w = threadIdx.x >> 6;
  int nw = blockDim.x >> 6;
  for (int ww = 0; ww < nw; ww++) {
    if (w == ww) {
      if (ww == 0) {
#pragma unroll
        for (int q = 0; q < DM / 2; q++) {
          red[lane * 66 + 2 * q]     = acc2[q].x;
          red[lane * 66 + 2 * q + 1] = acc2[q].y;
        }
        red[64 * 66 + lane] = den;
      } else {
#pragma unroll
        for (int q = 0; q < DM / 2; q++) {
          red[lane * 66 + 2 * q]     += acc2[q].x;
          red[lane * 66 + 2 * q + 1] += acc2[q].y;
        }
        red[64 * 66 + lane] += den;
      }
    }
    __syncthreads();
  }
  float* pb = partial + (size_t)blockIdx.x * PARTIAL_STRIDE;
  for (int i = threadIdx.x; i < CL * DM; i += blockDim.x)
    pb[i] = red[(i >> 6) * 66 + (i & 63)];
  if (threadIdx.x < 64) pb[CL * DM + threadIdx.x] = red[64 * 66 + threadIdx.x];
}

// C_0 partials: membership from normalized u0_raw, squared, accumulate um * x.
__global__ __launch_bounds__(256, 2)
void fcm_init(const float* __restrict__ data, const float* __restrict__ u0,
              float* __restrict__ partial, int N, int ntiles, int totwaves) {
  __shared__ float red[64 * 66 + 64];
  int lane = threadIdx.x & 63;
  int wv = blockIdx.x * (blockDim.x >> 6) + __builtin_amdgcn_readfirstlane(threadIdx.x >> 6);
  f32x2 acc2[DM / 2];
#pragma unroll
  for (int q = 0; q < DM / 2; q++) acc2[q] = f32x2{0.0f, 0.0f};
  float den = 0.0f;
  for (int t = wv; t < ntiles; t += totwaves) {
    int base = t * 64;
    int np = min(64, N - base);
    for (int p = 0; p < np; p++) {
      int pt = base + p;                       // wave-uniform
      float u = u0[(size_t)pt * CL + lane];    // coalesced
      float s = wave_sum(u);
      float un = u * fast_rcp(s);
      float um = un * un;
      den += um;
      const f32x2* xr = (const f32x2*)(data + (size_t)pt * DM);  // uniform row
      f32x2 um2 = f32x2{um, um};
#pragma unroll
      for (int q = 0; q < DM / 2; q++) acc2[q] += um2 * xr[q];
    }
  }
  block_reduce_store(red, acc2, den, partial);
}

// One fused FCM update pass: C_cur -> partials for C_next. Lane j owns cluster j.
__global__ __launch_bounds__(256, 2)
void fcm_update(const float* __restrict__ data, const float* __restrict__ x2,
                const float* __restrict__ Ccur, float* __restrict__ partial,
                const int* __restrict__ done, int N, int ntiles, int totwaves) {
  if (*done) return;   // frozen after convergence (wave-uniform)
  __shared__ float red[64 * 66 + 64];
  int lane = threadIdx.x & 63;
  int wv = blockIdx.x * (blockDim.x >> 6) + __builtin_amdgcn_readfirstlane(threadIdx.x >> 6);
  f32x2 Crow2[DM / 2];
#pragma unroll
  for (int q = 0; q < DM / 2; q++)
    Crow2[q] = ((const f32x2*)(Ccur + lane * DM))[q];
  float c2 = 0.0f;
#pragma unroll
  for (int q = 0; q < DM / 2; q++)
    c2 = fmaf(Crow2[q].x, Crow2[q].x, fmaf(Crow2[q].y, Crow2[q].y, c2));
  f32x2 acc2[DM / 2];
#pragma unroll
  for (int q = 0; q < DM / 2; q++) acc2[q] = f32x2{0.0f, 0.0f};
  float den = 0.0f;
  for (int t = wv; t < ntiles; t += totwaves) {
    int base = t * 64;
    int np = min(64, N - base);
    for (int p = 0; p < np; p++) {
      int pt = base + p;                             // wave-uniform
      const f32x2* xr = (const f32x2*)(data + (size_t)pt * DM);  // uniform row
      f32x2 s0 = f32x2{0.0f, 0.0f}, s1 = f32x2{0.0f, 0.0f};
#pragma unroll
      for (int q = 0; q < DM / 4; q++) {
        s0 += Crow2[2 * q]     * xr[2 * q];       // -> v_pk_fma_f32
        s1 += Crow2[2 * q + 1] * xr[2 * q + 1];
      }
      float dot = (s0.x + s0.y) + (s1.x + s1.y);
      float dist = fmaxf(x2[pt] + c2 - 2.0f * dot, 0.0f);  // jnp.maximum(...,0)
      float wgt = fast_rcp(dist);                // d^(-p/2) with p=2
      float s = wave_sum(wgt);                   // DPP, VALU pipe
      float u = wgt * fast_rcp(s);
      float um = u * u;                          // U^m, m=2
      den += um;
      f32x2 um2 = f32x2{um, um};
#pragma unroll
      for (int q = 0; q < DM / 2; q++) acc2[q] += um2 * xr[q];
    }
  }
  block_reduce_store(red, acc2, den, partial);
}

// Sum partials -> C_new; accumulate Frobenius diff; LAST block (ticket) does the
// convergence check (merged former fcm_check) and resets diffac/ticket.
__global__ __launch_bounds__(1024, 1)
void fcm_reduce(const float* __restrict__ partial, float* __restrict__ Cnew,
                const float* __restrict__ Cold, float* __restrict__ out,
                float* __restrict__ diffac, int* __restrict__ done,
                int* __restrict__ ticket, int compute_diff, int nb) {
  if (compute_diff && *done) return;
  __shared__ float sm[16 * 64];
  __shared__ float sden[1024];
  __shared__ int lastflag;
  __shared__ float sdiff;
  int j = blockIdx.x;
  int tid = threadIdx.x;
  int d = tid & 63;
  int slice = tid >> 6;                 // 0..15
  float s = 0.0f;
  for (int b = slice; b < nb; b += 16)  // coalesced: 64 consecutive floats per wave
    s += partial[(size_t)b * PARTIAL_STRIDE + j * DM + d];
  sm[slice * 64 + d] = s;
  float dv = 0.0f;
  for (int b = tid; b < nb; b += 1024)
    dv += partial[(size_t)b * PARTIAL_STRIDE + CL * DM + j];
  sden[tid] = dv;
  __syncthreads();
#pragma unroll
  for (int st = 8; st; st >>= 1) {
    if (slice < st) sm[slice * 64 + d] += sm[(slice + st) * 64 + d];
    __syncthreads();
  }
#pragma unroll
  for (int st = 512; st >= 64; st >>= 1) {
    if (tid < st) sden[tid] += sden[tid + st];
    __syncthreads();
  }
  if (tid < 64) {
    float denj = wave_sum(sden[tid]);   // total den for cluster j
    float c = sm[tid] / denj;           // slice-0 row holds the full sum
    Cnew[j * DM + tid] = c;
    if (compute_diff) {
      float df = c - Cold[j * DM + tid];
      float tot = wave_sum(df * df);
      if (tid == 0) atomicAdd(diffac, tot);
    }
  }
  if (!compute_diff) return;
  __syncthreads();
  if (tid == 0) {
    __threadfence();                    // order our diffac add before ticket
    int t = atomicAdd(ticket, 1);
    lastflag = (t == (int)gridDim.x - 1);
  }
  __syncthreads();
  if (!lastflag) return;
  if (tid == 0) sdiff = atomicAdd(diffac, 0.0f);  // atomic read: all adds done
  __syncthreads();
  if (sdiff < 1e-16f) {                 // diff < 1e-8  <=>  diff^2 < 1e-16
    for (int i = tid; i < CL * DM; i += 1024) out[i] = Cold[i];
    if (tid == 0) *done = 1;
  }
  if (tid == 0) { *diffac = 0.0f; *ticket = 0; }
}

// If never converged, V = C_25.
__global__ void fcm_final(const float* __restrict__ Clast, float* __restrict__ out,
                          const int* __restrict__ done) {
  if (*done) return;
  int i = blockIdx.x * blockDim.x + threadIdx.x;
  if (i < CL * DM) out[i] = Clast[i];
}

extern "C" void kernel_launch(void* const* d_in, const int* in_sizes, int n_in,
                              void* d_out, int out_size, void* d_ws, size_t ws_size,
                              hipStream_t stream) {
  const float* data = (const float*)d_in[0];
  const float* u0   = (const float*)d_in[1];
  float* out = (float*)d_out;
  int N = in_sizes[0] / DM;            // 300000
  int ntiles = (N + 63) / 64;          // 4688

  float* ws = (float*)d_ws;
  size_t Noff = ((size_t)N + 15) & ~(size_t)15;
  float* x2 = ws;                                  // N
  float* C0 = ws + Noff;                           // 4096
  float* C1 = C0 + CL * DM;                        // 4096
  float* diffac = C1 + CL * DM;                    // 1
  int* done = (int*)(diffac + 1);                  // 1
  int* ticket = (int*)(diffac + 2);                // 1
  float* partial = diffac + 16;

  size_t used = Noff + 2 * CL * DM + 16;
  size_t avail = (ws_size / 4 > used) ? (ws_size / 4 - used) / PARTIAL_STRIDE : 0;
  int nb = (int)(avail < MAX_BLOCKS ? avail : MAX_BLOCKS);   // runtime ws clamp
  if (nb < 1) nb = 1;
  int totwaves = nb * 4;

  hipLaunchKernelGGL(fcm_prep, dim3((N + 255) / 256), dim3(256), 0, stream,
                     data, x2, diffac, done, ticket, N);
  hipLaunchKernelGGL(fcm_init, dim3(nb), dim3(256), 0, stream,
                     data, u0, partial, N, ntiles, totwaves);
  hipLaunchKernelGGL(fcm_reduce, dim3(64), dim3(1024), 0, stream,
                     partial, C0, C1, out, diffac, done, ticket, 0, nb);

  float* bufs[2] = {C0, C1};
  for (int k = 0; k < MAX_ITER; k++) {
    float* Cc = bufs[k & 1];
    float* Cn = bufs[(k + 1) & 1];
    hipLaunchKernelGGL(fcm_update, dim3(nb), dim3(256), 0, stream,
                       data, x2, Cc, partial, done, N, ntiles, totwaves);
    hipLaunchKernelGGL(fcm_reduce, dim3(64), dim3(1024), 0, stream,
                       partial, Cn, Cc, out, diffac, done, ticket, 1, nb);
  }
  hipLaunchKernelGGL(fcm_final, dim3(16), dim3(256), 0, stream,
                     bufs[1], out, done);
}

// Round 4
// 432.417 us; speedup vs baseline: 6.7672x; 3.1296x over previous
//
#include <hip/hip_runtime.h>

// Fuzzy c-means on MI355X. N=300000, D=64, c=64, m=2 (p=2), 25 updates + init.
// R4: MFMA rewrite. fp32 vector floor is ~814us for the 2 GEMMs; bf16 MFMA makes
// GEMM time negligible. Fused per-tile kernel: stage X/XT bf16 in LDS; wave w owns
// 16 clusters: S = X@C^T (mfma 16x16x32 bf16), dist/rcp, rowsum via DPP butterfly +
// LDS cross-wave combine, um=(w*rr)^2 -> bf16 umT in LDS -> mfma umT@X accumulate.
// Init shares the kernel (template INIT: W := u0 loads instead of distances).
// Tolerance analysis: bf16 um noise ~3e-7 rms averages over 300K pts -> center
// noise ~2e-6 vs 9.9e-5 threshold.

#define DM 64
#define CL 64
#define PARTIAL_STRIDE 4160      // 64*64 num + 64 den
#define MAX_ITER 25
#define MAX_BLOCKS 1024
#define LDP 72                   // padded row length (bf16) for Xb/XTb/umT

typedef __attribute__((ext_vector_type(8))) short bf16x8;   // MFMA A/B frag (4 VGPRs)
typedef __attribute__((ext_vector_type(4))) float f32x4;    // MFMA C/D frag

__device__ __forceinline__ unsigned f2bf1(float f) {        // fp32 -> bf16 (RNE)
  unsigned u = __builtin_bit_cast(unsigned, f);
  return (u + 0x7FFFu + ((u >> 16) & 1u)) >> 16;
}
__device__ __forceinline__ unsigned pkbf(float a, float b) {
  return f2bf1(a) | (f2bf1(b) << 16);
}

// 64-lane sum (reduce kernel only): DPP row reduce + bcast, result via lane 63.
__device__ __forceinline__ float wave_sum(float v) {
#define DPPADD(ctrl, rmask)                                                  \
  v += __builtin_bit_cast(float, __builtin_amdgcn_update_dpp(                \
           0, __builtin_bit_cast(int, v), ctrl, rmask, 0xf, false));
  DPPADD(0x111, 0xf)   // row_shr:1
  DPPADD(0x112, 0xf)   // row_shr:2
  DPPADD(0x114, 0xf)   // row_shr:4
  DPPADD(0x118, 0xf)   // row_shr:8
  DPPADD(0x142, 0xa)   // row_bcast:15
  DPPADD(0x143, 0xc)   // row_bcast:31
#undef DPPADD
  return __builtin_bit_cast(
      float, __builtin_amdgcn_readlane(__builtin_bit_cast(int, v), 63));
}

// all-lanes sum within each 16-lane group: xor1, xor2, xor7(=xor4 after quads
// equal), xor15(=xor8 after 8-groups equal). Pure VALU (DPP).
__device__ __forceinline__ float group16_sum(float v) {
#define DPPADD(ctrl)                                                         \
  v += __builtin_bit_cast(float, __builtin_amdgcn_update_dpp(                \
           0, __builtin_bit_cast(int, v), ctrl, 0xf, 0xf, false));
  DPPADD(0xB1)    // quad_perm [1,0,3,2]  (xor 1)
  DPPADD(0x4E)    // quad_perm [2,3,0,1]  (xor 2)
  DPPADD(0x141)   // row_half_mirror      (pairs quads within 8)
  DPPADD(0x140)   // row_mirror           (pairs 8-groups within 16)
#undef DPPADD
  return v;
}

// x2[i] = ||x_i||^2 precompute + flag reset
__global__ void fcm_prep(const float* __restrict__ data, float* __restrict__ x2,
                         float* __restrict__ diffac, int* __restrict__ done,
                         int* __restrict__ ticket, int N) {
  int i = blockIdx.x * blockDim.x + threadIdx.x;
  if (i == 0) { *diffac = 0.0f; *done = 0; *ticket = 0; }
  if (i < N) {
    const float4* r = (const float4*)(data + (size_t)i * DM);
    float s = 0.0f;
#pragma unroll
    for (int q = 0; q < DM / 4; q++) {
      float4 v = r[q];
      s = fmaf(v.x, v.x, s); s = fmaf(v.y, v.y, s);
      s = fmaf(v.z, v.z, s); s = fmaf(v.w, v.w, s);
    }
    x2[i] = s;
  }
}

// Fused pass. INIT: W := u0 (raw memberships). else: W := 1/dist via MFMA GEMM1.
// Both: um = (W * rcp(rowsum))^2 -> bf16 umT -> MFMA GEMM2 accumulate -> partial.
template <bool INIT>
__global__ __launch_bounds__(256, 3)
void fcm_pass(const float* __restrict__ data, const float* __restrict__ x2,
              const float* __restrict__ CU,   // INIT: u0[N][64]; else C[64][64]
              float* __restrict__ partial, const int* __restrict__ done,
              int N, int ntiles) {
  if (!INIT && *done) return;
  __shared__ __align__(16) unsigned short Xb[64 * LDP];   // X[p][d] bf16
  __shared__ __align__(16) unsigned short XTb[64 * LDP];  // X^T[d][p] bf16
  __shared__ __align__(16) unsigned short umT[64 * LDP];  // um^T[j][p] bf16
  __shared__ __align__(16) float rpart[4 * 64];           // per-wave rowsum partials
  __shared__ __align__(16) float rrs[64];                 // rcp(rowsum[p])
  __shared__ __align__(16) float x2s[64];

  const int tid  = threadIdx.x;
  const int w    = __builtin_amdgcn_readfirstlane(tid >> 6);  // wave id: cluster tile
  const int col  = tid & 15;
  const int quad = (tid >> 4) & 3;

  // ---- per-kernel prep: C row j=16w+col -> c2[j] (fp32) + bf16 B-frags ----
  bf16x8 cf0, cf1;
  float c2j = 0.0f;
  if (!INIT) {
    const float* crow = CU + (size_t)(16 * w + col) * DM;
    float4 ca = *(const float4*)(crow + quad * 8);
    float4 cb = *(const float4*)(crow + quad * 8 + 4);
    float4 cc = *(const float4*)(crow + 32 + quad * 8);
    float4 cd = *(const float4*)(crow + 32 + quad * 8 + 4);
    float cp = ca.x*ca.x + ca.y*ca.y + ca.z*ca.z + ca.w*ca.w
             + cb.x*cb.x + cb.y*cb.y + cb.z*cb.z + cb.w*cb.w
             + cc.x*cc.x + cc.y*cc.y + cc.z*cc.z + cc.w*cc.w
             + cd.x*cd.x + cd.y*cd.y + cd.z*cd.z + cd.w*cd.w;
    cp += __shfl_xor(cp, 16, 64);
    cp += __shfl_xor(cp, 32, 64);
    c2j = cp;
    union { bf16x8 v; unsigned u[4]; } P0, P1;
    P0.u[0] = pkbf(ca.x, ca.y); P0.u[1] = pkbf(ca.z, ca.w);
    P0.u[2] = pkbf(cb.x, cb.y); P0.u[3] = pkbf(cb.z, cb.w);
    P1.u[0] = pkbf(cc.x, cc.y); P1.u[1] = pkbf(cc.z, cc.w);
    P1.u[2] = pkbf(cd.x, cd.y); P1.u[3] = pkbf(cd.z, cd.w);
    cf0 = P0.v; cf1 = P1.v;
  }

  f32x4 D2[4];   // C-partial accumulator: tiles (jt=w, dt=0..3)
#pragma unroll
  for (int dt = 0; dt < 4; dt++) D2[dt] = f32x4{0.f, 0.f, 0.f, 0.f};
  float den = 0.0f;

  for (int t = blockIdx.x; t < ntiles; t += gridDim.x) {
    const int base = t * 64;
    const int np = min(64, N - base);
    __syncthreads();   // previous iteration's LDS reads done

    // ---- staging: X fp32 -> Xb + XTb bf16 (cooperative, coalesced) ----
    for (int i = tid; i < 1024; i += 256) {
      int p = i >> 4;
      int d4 = (i & 15) * 4;
      float4 v = {0.f, 0.f, 0.f, 0.f};
      if (p < np) v = *(const float4*)(data + (size_t)(base + p) * DM + d4);
      unsigned long long w64 = (unsigned long long)pkbf(v.x, v.y) |
                               ((unsigned long long)pkbf(v.z, v.w) << 32);
      *(unsigned long long*)(void*)&Xb[p * LDP + d4] = w64;
      XTb[(d4 + 0) * LDP + p] = (unsigned short)f2bf1(v.x);
      XTb[(d4 + 1) * LDP + p] = (unsigned short)f2bf1(v.y);
      XTb[(d4 + 2) * LDP + p] = (unsigned short)f2bf1(v.z);
      XTb[(d4 + 3) * LDP + p] = (unsigned short)f2bf1(v.w);
    }
    if (tid < 64) x2s[tid] = (base + tid < N) ? x2[base + tid] : 0.0f;
    __syncthreads();

    // ---- W: either GEMM1 (dist) or u0 loads. lane view: value (p=pt*16+quad*4+r,
    //      j=16w+col) in reg W[pt][r] (MFMA C/D layout). ----
    float W[4][4];
    if (INIT) {
#pragma unroll
      for (int pt = 0; pt < 4; pt++)
#pragma unroll
        for (int r = 0; r < 4; r++) {
          int pl = pt * 16 + quad * 4 + r;
          W[pt][r] = (pl < np)
              ? CU[(size_t)(base + pl) * CL + 16 * w + col] : 0.0f;
        }
    } else {
#pragma unroll
      for (int pt = 0; pt < 4; pt++) {
        bf16x8 a0 = *(const bf16x8*)(const void*)&Xb[(pt * 16 + col) * LDP + quad * 8];
        bf16x8 a1 = *(const bf16x8*)(const void*)&Xb[(pt * 16 + col) * LDP + 32 + quad * 8];
        f32x4 s = f32x4{0.f, 0.f, 0.f, 0.f};
        s = __builtin_amdgcn_mfma_f32_16x16x32_bf16(a0, cf0, s, 0, 0, 0);
        s = __builtin_amdgcn_mfma_f32_16x16x32_bf16(a1, cf1, s, 0, 0, 0);
        f32x4 x2v = *(const f32x4*)(const void*)&x2s[pt * 16 + quad * 4];
#pragma unroll
        for (int r = 0; r < 4; r++) {
          float dist = fmaxf(fmaf(-2.0f, s[r], x2v[r] + c2j), 0.0f);
          W[pt][r] = __builtin_amdgcn_rcpf(dist);   // d^(-p/2), p=2
        }
      }
    }

    // ---- rowsum over this wave's 16 clusters (DPP butterfly), write partials ----
    float rs[4][4];
#pragma unroll
    for (int pt = 0; pt < 4; pt++)
#pragma unroll
      for (int r = 0; r < 4; r++) rs[pt][r] = group16_sum(W[pt][r]);
    if (col == 0) {
#pragma unroll
      for (int pt = 0; pt < 4; pt++) {
        float4 v4 = {rs[pt][0], rs[pt][1], rs[pt][2], rs[pt][3]};
        *(float4*)(void*)&rpart[w * 64 + pt * 16 + quad * 4] = v4;
      }
    }
    __syncthreads();
    if (tid < 64) {
      float rt = rpart[tid] + rpart[64 + tid] + rpart[128 + tid] + rpart[192 + tid];
      rrs[tid] = __builtin_amdgcn_rcpf(rt);
    }
    __syncthreads();

    // ---- um = (W * rr)^2, mask padded p, den accumulate, bf16 umT write ----
#pragma unroll
    for (int pt = 0; pt < 4; pt++) {
      f32x4 rrv = *(const f32x4*)(const void*)&rrs[pt * 16 + quad * 4];
      float um[4];
#pragma unroll
      for (int r = 0; r < 4; r++) {
        float u = W[pt][r] * rrv[r];
        float m = u * u;
        um[r] = (pt * 16 + quad * 4 + r < np) ? m : 0.0f;
        den += um[r];
      }
      unsigned long long w64 = (unsigned long long)pkbf(um[0], um[1]) |
                               ((unsigned long long)pkbf(um[2], um[3]) << 32);
      *(unsigned long long*)(void*)&umT[(16 * w + col) * LDP + pt * 16 + quad * 4] = w64;
    }
    // no barrier: each wave reads back only the umT rows it wrote (lgkmcnt order)

    // ---- GEMM2: D2[jt=w][dt] += um^T @ X ----
#pragma unroll
    for (int pb = 0; pb < 2; pb++) {
      bf16x8 au = *(const bf16x8*)(const void*)&umT[(16 * w + col) * LDP + pb * 32 + quad * 8];
#pragma unroll
      for (int dt = 0; dt < 4; dt++) {
        bf16x8 bx = *(const bf16x8*)(const void*)&XTb[(dt * 16 + col) * LDP + pb * 32 + quad * 8];
        D2[dt] = __builtin_amdgcn_mfma_f32_16x16x32_bf16(au, bx, D2[dt], 0, 0, 0);
      }
    }
  }

  // ---- epilogue: fold den across quads, write per-block partial ----
  den += __shfl_xor(den, 16, 64);
  den += __shfl_xor(den, 32, 64);
  float* pb = partial + (size_t)blockIdx.x * PARTIAL_STRIDE;
  if (quad == 0) pb[CL * DM + 16 * w + col] = den;
#pragma unroll
  for (int dt = 0; dt < 4; dt++)
#pragma unroll
    for (int r = 0; r < 4; r++)
      pb[(size_t)(16 * w + quad * 4 + r) * DM + dt * 16 + col] = D2[dt][r];
}

// Sum partials -> C_new; Frobenius diff; last block (ticket) does convergence check.
__global__ __launch_bounds__(1024, 1)
void fcm_reduce(const float* __restrict__ partial, float* __restrict__ Cnew,
                const float* __restrict__ Cold, float* __restrict__ out,
                float* __restrict__ diffac, int* __restrict__ done,
                int* __restrict__ ticket, int compute_diff, int nb) {
  if (compute_diff && *done) return;
  __shared__ float sm[16 * 64];
  __shared__ float sden[1024];
  __shared__ int lastflag;
  __shared__ float sdiff;
  int j = blockIdx.x;
  int tid = threadIdx.x;
  int d = tid & 63;
  int slice = tid >> 6;
  float s = 0.0f;
  for (int b = slice; b < nb; b += 16)
    s += partial[(size_t)b * PARTIAL_STRIDE + j * DM + d];
  sm[slice * 64 + d] = s;
  float dv = 0.0f;
  for (int b = tid; b < nb; b += 1024)
    dv += partial[(size_t)b * PARTIAL_STRIDE + CL * DM + j];
  sden[tid] = dv;
  __syncthreads();
#pragma unroll
  for (int st = 8; st; st >>= 1) {
    if (slice < st) sm[slice * 64 + d] += sm[(slice + st) * 64 + d];
    __syncthreads();
  }
#pragma unroll
  for (int st = 512; st >= 64; st >>= 1) {
    if (tid < st) sden[tid] += sden[tid + st];
    __syncthreads();
  }
  if (tid < 64) {
    float denj = wave_sum(sden[tid]);
    float c = sm[tid] / denj;
    Cnew[j * DM + tid] = c;
    if (compute_diff) {
      float df = c - Cold[j * DM + tid];
      float tot = wave_sum(df * df);
      if (tid == 0) atomicAdd(diffac, tot);
    }
  }
  if (!compute_diff) return;
  __syncthreads();
  if (tid == 0) {
    __threadfence();
    int t = atomicAdd(ticket, 1);
    lastflag = (t == (int)gridDim.x - 1);
  }
  __syncthreads();
  if (!lastflag) return;
  if (tid == 0) sdiff = atomicAdd(diffac, 0.0f);
  __syncthreads();
  if (sdiff < 1e-16f) {                 // diff < 1e-8  <=>  diff^2 < 1e-16
    for (int i = tid; i < CL * DM; i += 1024) out[i] = Cold[i];
    if (tid == 0) *done = 1;
  }
  if (tid == 0) { *diffac = 0.0f; *ticket = 0; }
}

// If never converged, V = C_25.
__global__ void fcm_final(const float* __restrict__ Clast, float* __restrict__ out,
                          const int* __restrict__ done) {
  if (*done) return;
  int i = blockIdx.x * blockDim.x + threadIdx.x;
  if (i < CL * DM) out[i] = Clast[i];
}

extern "C" void kernel_launch(void* const* d_in, const int* in_sizes, int n_in,
                              void* d_out, int out_size, void* d_ws, size_t ws_size,
                              hipStream_t stream) {
  const float* data = (const float*)d_in[0];
  const float* u0   = (const float*)d_in[1];
  float* out = (float*)d_out;
  int N = in_sizes[0] / DM;            // 300000
  int ntiles = (N + 63) / 64;          // 4688

  float* ws = (float*)d_ws;
  size_t Noff = ((size_t)N + 15) & ~(size_t)15;
  float* x2 = ws;
  float* C0 = ws + Noff;
  float* C1 = C0 + CL * DM;
  float* diffac = C1 + CL * DM;
  int* done = (int*)(diffac + 1);
  int* ticket = (int*)(diffac + 2);
  float* partial = diffac + 16;

  size_t used = Noff + 2 * CL * DM + 16;
  size_t avail = (ws_size / 4 > used) ? (ws_size / 4 - used) / PARTIAL_STRIDE : 0;
  int nb = (int)(avail < MAX_BLOCKS ? avail : MAX_BLOCKS);
  if (nb < 1) nb = 1;

  hipLaunchKernelGGL(fcm_prep, dim3((N + 255) / 256), dim3(256), 0, stream,
                     data, x2, diffac, done, ticket, N);
  hipLaunchKernelGGL((fcm_pass<true>), dim3(nb), dim3(256), 0, stream,
                     data, x2, u0, partial, done, N, ntiles);
  hipLaunchKernelGGL(fcm_reduce, dim3(64), dim3(1024), 0, stream,
                     partial, C0, C1, out, diffac, done, ticket, 0, nb);

  float* bufs[2] = {C0, C1};
  for (int k = 0; k < MAX_ITER; k++) {
    float* Cc = bufs[k & 1];
    float* Cn = bufs[(k + 1) & 1];
    hipLaunchKernelGGL((fcm_pass<false>), dim3(nb), dim3(256), 0, stream,
                       data, x2, Cc, partial, done, N, ntiles);
    hipLaunchKernelGGL(fcm_reduce, dim3(64), dim3(1024), 0, stream,
                       partial, Cn, Cc, out, diffac, done, ticket, 1, nb);
  }
  hipLaunchKernelGGL(fcm_final, dim3(16), dim3(256), 0, stream,
                     bufs[1], out, done);
}

// Round 5
// 427.050 us; speedup vs baseline: 6.8522x; 1.0126x over previous
//
#include <hip/hip_runtime.h>

// Fuzzy c-means on MI355X. N=300000, D=64, c=64, m=2 (p=2), 25 updates + init.
// R4: MFMA rewrite (432us). R5: passes were HBM-bound re-fetching 76.8MB fp32
// that gets bf16-rounded in LDS anyway -> prep now writes a bf16 copy (38.4MB)
// and passes stage from it (bit-identical math to R4). nb 1024->512 halves
// partial traffic. Per-iteration HBM: ~48MB vs ~94MB.

#define DM 64
#define CL 64
#define PARTIAL_STRIDE 4160      // 64*64 num + 64 den
#define MAX_ITER 25
#define MAX_BLOCKS 512
#define LDP 72                   // padded row length (bf16) for Xb/XTb/umT

typedef __attribute__((ext_vector_type(8))) short bf16x8;   // MFMA A/B frag (4 VGPRs)
typedef __attribute__((ext_vector_type(4))) float f32x4;    // MFMA C/D frag

__device__ __forceinline__ unsigned f2bf1(float f) {        // fp32 -> bf16 (RNE)
  unsigned u = __builtin_bit_cast(unsigned, f);
  return (u + 0x7FFFu + ((u >> 16) & 1u)) >> 16;
}
__device__ __forceinline__ unsigned pkbf(float a, float b) {
  return f2bf1(a) | (f2bf1(b) << 16);
}

// 64-lane sum (reduce kernel only): DPP row reduce + bcast, result via lane 63.
__device__ __forceinline__ float wave_sum(float v) {
#define DPPADD(ctrl, rmask)                                                  \
  v += __builtin_bit_cast(float, __builtin_amdgcn_update_dpp(                \
           0, __builtin_bit_cast(int, v), ctrl, rmask, 0xf, false));
  DPPADD(0x111, 0xf)   // row_shr:1
  DPPADD(0x112, 0xf)   // row_shr:2
  DPPADD(0x114, 0xf)   // row_shr:4
  DPPADD(0x118, 0xf)   // row_shr:8
  DPPADD(0x142, 0xa)   // row_bcast:15
  DPPADD(0x143, 0xc)   // row_bcast:31
#undef DPPADD
  return __builtin_bit_cast(
      float, __builtin_amdgcn_readlane(__builtin_bit_cast(int, v), 63));
}

// all-lanes sum within each 16-lane group, pure VALU (DPP).
__device__ __forceinline__ float group16_sum(float v) {
#define DPPADD(ctrl)                                                         \
  v += __builtin_bit_cast(float, __builtin_amdgcn_update_dpp(                \
           0, __builtin_bit_cast(int, v), ctrl, 0xf, 0xf, false));
  DPPADD(0xB1)    // quad_perm [1,0,3,2]  (xor 1)
  DPPADD(0x4E)    // quad_perm [2,3,0,1]  (xor 2)
  DPPADD(0x141)   // row_half_mirror
  DPPADD(0x140)   // row_mirror
#undef DPPADD
  return v;
}

// x2[i] = ||x_i||^2 (fp32, matches reference) + bf16 copy of data + flag reset.
__global__ void fcm_prep(const float* __restrict__ data, float* __restrict__ x2,
                         unsigned short* __restrict__ xbf,
                         float* __restrict__ diffac, int* __restrict__ done,
                         int* __restrict__ ticket, int N) {
  int i = blockIdx.x * blockDim.x + threadIdx.x;
  if (i == 0) { *diffac = 0.0f; *done = 0; *ticket = 0; }
  if (i < N) {
    const float4* r = (const float4*)(data + (size_t)i * DM);
    unsigned short* xo = xbf + (size_t)i * DM;
    float s = 0.0f;
#pragma unroll
    for (int q = 0; q < DM / 4; q++) {
      float4 v = r[q];
      s = fmaf(v.x, v.x, s); s = fmaf(v.y, v.y, s);
      s = fmaf(v.z, v.z, s); s = fmaf(v.w, v.w, s);
      uint2 pk = {pkbf(v.x, v.y), pkbf(v.z, v.w)};
      *(uint2*)(void*)(xo + q * 4) = pk;
    }
    x2[i] = s;
  }
}

// Fused pass. INIT: W := u0 (raw memberships). else: W := 1/dist via MFMA GEMM1.
// Both: um = (W * rcp(rowsum))^2 -> bf16 umT -> MFMA GEMM2 accumulate -> partial.
template <bool INIT>
__global__ __launch_bounds__(256, 3)
void fcm_pass(const unsigned short* __restrict__ xbf, const float* __restrict__ x2,
              const float* __restrict__ CU,   // INIT: u0[N][64]; else C[64][64]
              float* __restrict__ partial, const int* __restrict__ done,
              int N, int ntiles) {
  if (!INIT && *done) return;
  __shared__ __align__(16) unsigned short Xb[64 * LDP];   // X[p][d] bf16
  __shared__ __align__(16) unsigned short XTb[64 * LDP];  // X^T[d][p] bf16
  __shared__ __align__(16) unsigned short umT[64 * LDP];  // um^T[j][p] bf16
  __shared__ __align__(16) float rpart[4 * 64];           // per-wave rowsum partials
  __shared__ __align__(16) float rrs[64];                 // rcp(rowsum[p])
  __shared__ __align__(16) float x2s[64];

  const int tid  = threadIdx.x;
  const int w    = __builtin_amdgcn_readfirstlane(tid >> 6);  // wave id: cluster tile
  const int col  = tid & 15;
  const int quad = (tid >> 4) & 3;

  // ---- per-kernel prep: C row j=16w+col -> c2[j] (fp32) + bf16 B-frags ----
  bf16x8 cf0, cf1;
  float c2j = 0.0f;
  if (!INIT) {
    const float* crow = CU + (size_t)(16 * w + col) * DM;
    float4 ca = *(const float4*)(crow + quad * 8);
    float4 cb = *(const float4*)(crow + quad * 8 + 4);
    float4 cc = *(const float4*)(crow + 32 + quad * 8);
    float4 cd = *(const float4*)(crow + 32 + quad * 8 + 4);
    float cp = ca.x*ca.x + ca.y*ca.y + ca.z*ca.z + ca.w*ca.w
             + cb.x*cb.x + cb.y*cb.y + cb.z*cb.z + cb.w*cb.w
             + cc.x*cc.x + cc.y*cc.y + cc.z*cc.z + cc.w*cc.w
             + cd.x*cd.x + cd.y*cd.y + cd.z*cd.z + cd.w*cd.w;
    cp += __shfl_xor(cp, 16, 64);
    cp += __shfl_xor(cp, 32, 64);
    c2j = cp;
    union { bf16x8 v; unsigned u[4]; } P0, P1;
    P0.u[0] = pkbf(ca.x, ca.y); P0.u[1] = pkbf(ca.z, ca.w);
    P0.u[2] = pkbf(cb.x, cb.y); P0.u[3] = pkbf(cb.z, cb.w);
    P1.u[0] = pkbf(cc.x, cc.y); P1.u[1] = pkbf(cc.z, cc.w);
    P1.u[2] = pkbf(cd.x, cd.y); P1.u[3] = pkbf(cd.z, cd.w);
    cf0 = P0.v; cf1 = P1.v;
  }

  f32x4 D2[4];   // C-partial accumulator: tiles (jt=w, dt=0..3)
#pragma unroll
  for (int dt = 0; dt < 4; dt++) D2[dt] = f32x4{0.f, 0.f, 0.f, 0.f};
  float den = 0.0f;

  for (int t = blockIdx.x; t < ntiles; t += gridDim.x) {
    const int base = t * 64;
    const int np = min(64, N - base);
    __syncthreads();   // previous iteration's LDS reads done

    // ---- staging: bf16 global -> Xb rows (b128) + XTb transpose (b16 scatter) ----
    for (int i = tid; i < 512; i += 256) {
      int p = i >> 3;             // 0..63
      int d8 = (i & 7) * 8;       // 0,8,..,56
      bf16x8 v = bf16x8{0, 0, 0, 0, 0, 0, 0, 0};
      if (p < np) v = *(const bf16x8*)(xbf + (size_t)(base + p) * DM + d8);
      *(bf16x8*)(void*)&Xb[p * LDP + d8] = v;
#pragma unroll
      for (int k = 0; k < 8; k++)
        XTb[(d8 + k) * LDP + p] = (unsigned short)v[k];
    }
    if (tid < 64) x2s[tid] = (base + tid < N) ? x2[base + tid] : 0.0f;
    __syncthreads();

    // ---- W: either GEMM1 (dist) or u0 loads. lane view (MFMA C/D layout):
    //      value (p=pt*16+quad*4+r, j=16w+col) in W[pt][r]. ----
    float W[4][4];
    if (INIT) {
#pragma unroll
      for (int pt = 0; pt < 4; pt++)
#pragma unroll
        for (int r = 0; r < 4; r++) {
          int pl = pt * 16 + quad * 4 + r;
          W[pt][r] = (pl < np)
              ? CU[(size_t)(base + pl) * CL + 16 * w + col] : 0.0f;
        }
    } else {
#pragma unroll
      for (int pt = 0; pt < 4; pt++) {
        bf16x8 a0 = *(const bf16x8*)(const void*)&Xb[(pt * 16 + col) * LDP + quad * 8];
        bf16x8 a1 = *(const bf16x8*)(const void*)&Xb[(pt * 16 + col) * LDP + 32 + quad * 8];
        f32x4 s = f32x4{0.f, 0.f, 0.f, 0.f};
        s = __builtin_amdgcn_mfma_f32_16x16x32_bf16(a0, cf0, s, 0, 0, 0);
        s = __builtin_amdgcn_mfma_f32_16x16x32_bf16(a1, cf1, s, 0, 0, 0);
        f32x4 x2v = *(const f32x4*)(const void*)&x2s[pt * 16 + quad * 4];
#pragma unroll
        for (int r = 0; r < 4; r++) {
          float dist = fmaxf(fmaf(-2.0f, s[r], x2v[r] + c2j), 0.0f);
          W[pt][r] = __builtin_amdgcn_rcpf(dist);   // d^(-p/2), p=2
        }
      }
    }

    // ---- rowsum over this wave's 16 clusters (DPP), cross-wave via LDS ----
    float rs[4][4];
#pragma unroll
    for (int pt = 0; pt < 4; pt++)
#pragma unroll
      for (int r = 0; r < 4; r++) rs[pt][r] = group16_sum(W[pt][r]);
    if (col == 0) {
#pragma unroll
      for (int pt = 0; pt < 4; pt++) {
        float4 v4 = {rs[pt][0], rs[pt][1], rs[pt][2], rs[pt][3]};
        *(float4*)(void*)&rpart[w * 64 + pt * 16 + quad * 4] = v4;
      }
    }
    __syncthreads();
    if (tid < 64) {
      float rt = rpart[tid] + rpart[64 + tid] + rpart[128 + tid] + rpart[192 + tid];
      rrs[tid] = __builtin_amdgcn_rcpf(rt);
    }
    __syncthreads();

    // ---- um = (W * rr)^2, mask padded p, den accumulate, bf16 umT write ----
#pragma unroll
    for (int pt = 0; pt < 4; pt++) {
      f32x4 rrv = *(const f32x4*)(const void*)&rrs[pt * 16 + quad * 4];
      float um[4];
#pragma unroll
      for (int r = 0; r < 4; r++) {
        float u = W[pt][r] * rrv[r];
        float m = u * u;
        um[r] = (pt * 16 + quad * 4 + r < np) ? m : 0.0f;
        den += um[r];
      }
      unsigned long long w64 = (unsigned long long)pkbf(um[0], um[1]) |
                               ((unsigned long long)pkbf(um[2], um[3]) << 32);
      *(unsigned long long*)(void*)&umT[(16 * w + col) * LDP + pt * 16 + quad * 4] = w64;
    }
    // no barrier: each wave reads back only the umT rows it wrote (lgkmcnt order)

    // ---- GEMM2: D2[jt=w][dt] += um^T @ X ----
#pragma unroll
    for (int pb = 0; pb < 2; pb++) {
      bf16x8 au = *(const bf16x8*)(const void*)&umT[(16 * w + col) * LDP + pb * 32 + quad * 8];
#pragma unroll
      for (int dt = 0; dt < 4; dt++) {
        bf16x8 bx = *(const bf16x8*)(const void*)&XTb[(dt * 16 + col) * LDP + pb * 32 + quad * 8];
        D2[dt] = __builtin_amdgcn_mfma_f32_16x16x32_bf16(au, bx, D2[dt], 0, 0, 0);
      }
    }
  }

  // ---- epilogue: fold den across quads, write per-block partial ----
  den += __shfl_xor(den, 16, 64);
  den += __shfl_xor(den, 32, 64);
  float* pb = partial + (size_t)blockIdx.x * PARTIAL_STRIDE;
  if (quad == 0) pb[CL * DM + 16 * w + col] = den;
#pragma unroll
  for (int dt = 0; dt < 4; dt++)
#pragma unroll
    for (int r = 0; r < 4; r++)
      pb[(size_t)(16 * w + quad * 4 + r) * DM + dt * 16 + col] = D2[dt][r];
}

// Sum partials -> C_new; Frobenius diff; last block (ticket) does convergence check.
__global__ __launch_bounds__(1024, 1)
void fcm_reduce(const float* __restrict__ partial, float* __restrict__ Cnew,
                const float* __restrict__ Cold, float* __restrict__ out,
                float* __restrict__ diffac, int* __restrict__ done,
                int* __restrict__ ticket, int compute_diff, int nb) {
  if (compute_diff && *done) return;
  __shared__ float sm[16 * 64];
  __shared__ float sden[1024];
  __shared__ int lastflag;
  __shared__ float sdiff;
  int j = blockIdx.x;
  int tid = threadIdx.x;
  int d = tid & 63;
  int slice = tid >> 6;
  float s = 0.0f;
  for (int b = slice; b < nb; b += 16)
    s += partial[(size_t)b * PARTIAL_STRIDE + j * DM + d];
  sm[slice * 64 + d] = s;
  float dv = 0.0f;
  for (int b = tid; b < nb; b += 1024)
    dv += partial[(size_t)b * PARTIAL_STRIDE + CL * DM + j];
  sden[tid] = dv;
  __syncthreads();
#pragma unroll
  for (int st = 8; st; st >>= 1) {
    if (slice < st) sm[slice * 64 + d] += sm[(slice + st) * 64 + d];
    __syncthreads();
  }
#pragma unroll
  for (int st = 512; st >= 64; st >>= 1) {
    if (tid < st) sden[tid] += sden[tid + st];
    __syncthreads();
  }
  if (tid < 64) {
    float denj = wave_sum(sden[tid]);
    float c = sm[tid] / denj;
    Cnew[j * DM + tid] = c;
    if (compute_diff) {
      float df = c - Cold[j * DM + tid];
      float tot = wave_sum(df * df);
      if (tid == 0) atomicAdd(diffac, tot);
    }
  }
  if (!compute_diff) return;
  __syncthreads();
  if (tid == 0) {
    __threadfence();
    int t = atomicAdd(ticket, 1);
    lastflag = (t == (int)gridDim.x - 1);
  }
  __syncthreads();
  if (!lastflag) return;
  if (tid == 0) sdiff = atomicAdd(diffac, 0.0f);
  __syncthreads();
  if (sdiff < 1e-16f) {                 // diff < 1e-8  <=>  diff^2 < 1e-16
    for (int i = tid; i < CL * DM; i += 1024) out[i] = Cold[i];
    if (tid == 0) *done = 1;
  }
  if (tid == 0) { *diffac = 0.0f; *ticket = 0; }
}

// If never converged, V = C_25.
__global__ void fcm_final(const float* __restrict__ Clast, float* __restrict__ out,
                          const int* __restrict__ done) {
  if (*done) return;
  int i = blockIdx.x * blockDim.x + threadIdx.x;
  if (i < CL * DM) out[i] = Clast[i];
}

extern "C" void kernel_launch(void* const* d_in, const int* in_sizes, int n_in,
                              void* d_out, int out_size, void* d_ws, size_t ws_size,
                              hipStream_t stream) {
  const float* data = (const float*)d_in[0];
  const float* u0   = (const float*)d_in[1];
  float* out = (float*)d_out;
  int N = in_sizes[0] / DM;            // 300000
  int ntiles = (N + 63) / 64;          // 4688

  float* ws = (float*)d_ws;
  size_t Noff = ((size_t)N + 15) & ~(size_t)15;
  float* x2 = ws;                                  // N fp32
  unsigned short* xbf = (unsigned short*)(ws + Noff);  // N*64 bf16 = N*32 float slots
  float* C0 = ws + Noff + (size_t)N * 32;
  float* C1 = C0 + CL * DM;
  float* diffac = C1 + CL * DM;
  int* done = (int*)(diffac + 1);
  int* ticket = (int*)(diffac + 2);
  float* partial = diffac + 16;

  size_t used = Noff + (size_t)N * 32 + 2 * CL * DM + 16;
  size_t avail = (ws_size / 4 > used) ? (ws_size / 4 - used) / PARTIAL_STRIDE : 0;
  int nb = (int)(avail < MAX_BLOCKS ? avail : MAX_BLOCKS);
  if (nb < 1) nb = 1;

  hipLaunchKernelGGL(fcm_prep, dim3((N + 255) / 256), dim3(256), 0, stream,
                     data, x2, xbf, diffac, done, ticket, N);
  hipLaunchKernelGGL((fcm_pass<true>), dim3(nb), dim3(256), 0, stream,
                     xbf, x2, u0, partial, done, N, ntiles);
  hipLaunchKernelGGL(fcm_reduce, dim3(64), dim3(1024), 0, stream,
                     partial, C0, C1, out, diffac, done, ticket, 0, nb);

  float* bufs[2] = {C0, C1};
  for (int k = 0; k < MAX_ITER; k++) {
    float* Cc = bufs[k & 1];
    float* Cn = bufs[(k + 1) & 1];
    hipLaunchKernelGGL((fcm_pass<false>), dim3(nb), dim3(256), 0, stream,
                       xbf, x2, Cc, partial, done, N, ntiles);
    hipLaunchKernelGGL(fcm_reduce, dim3(64), dim3(1024), 0, stream,
                       partial, Cn, Cc, out, diffac, done, ticket, 1, nb);
  }
  hipLaunchKernelGGL(fcm_final, dim3(16), dim3(256), 0, stream,
                     bufs[1], out, done);
}